// Round 13
// baseline (186.645 us; speedup 1.0000x reference)
//
#include <hip/hip_runtime.h>
#include <hip/hip_bf16.h>
#include <math.h>

#define N_NODES 4096
#define N_EDGES 131072
#define BCAP 80                        // bucket capacity per row (Poisson(32): P(>80)~1e-12)
#define DIN 148
#define DHID 128
#define DOUT 148
#define KP 160
#define NITER 6

typedef __attribute__((ext_vector_type(8))) _Float16 half8;
typedef __attribute__((ext_vector_type(4))) float f32x4;

__device__ inline float h2f(unsigned e) {
    union { unsigned short u; _Float16 h; } cv;
    cv.u = (unsigned short)(e & 0xffffu);
    return (float)cv.h;
}

// ---------------- prep: weight transposes + dedup into fixed-stride buckets ----------------
__global__ __launch_bounds__(256) void prep_kernel(const int* __restrict__ ei,
                                                   const float* __restrict__ W1,
                                                   const float* __restrict__ Wd,
                                                   float* __restrict__ W1T,
                                                   float* __restrict__ WdT,
                                                   unsigned* __restrict__ bitmap,
                                                   unsigned* __restrict__ bucket,
                                                   int* __restrict__ rowdeg,
                                                   int* __restrict__ coldeg) {
    int gtid = blockIdx.x * 256 + threadIdx.x;          // 0..131071
    if (gtid < DIN * DHID) {                            // W1T[k*128+d] = W1[d*148+k]
        int kk = gtid >> 7, d = gtid & 127;
        W1T[gtid] = W1[d * DIN + kk];
    } else if (gtid < DIN * DHID + DHID * DOUT) {       // WdT[h*148+o] = Wd[o*128+h]
        int i2 = gtid - DIN * DHID;
        int h = i2 / DOUT, o = i2 - h * DOUT;
        WdT[i2] = Wd[o * DHID + h];
    }
    int i = ei[gtid] & (N_NODES - 1);
    int j = ei[gtid + N_EDGES] & (N_NODES - 1);
    unsigned pos = (unsigned)i * (unsigned)N_NODES + (unsigned)j;
    unsigned w = pos >> 5, m = 1u << (pos & 31u);
    unsigned old = atomicOr(&bitmap[w], m);
    if (!(old & m)) {
        int p = atomicAdd(&rowdeg[i], 1);
        if (p < BCAP) bucket[i * BCAP + p] = (unsigned)j;
        atomicAdd(&coldeg[j], 1);
    }
}

// ---------------- finalize: pack coefs in place (pad slots already zero) + acoef + linear1 ----------------
__global__ __launch_bounds__(256) void finalize_kernel(unsigned* __restrict__ bucket,
                                                       const int* __restrict__ rowdeg,
                                                       const int* __restrict__ coldeg,
                                                       float* __restrict__ acoef,
                                                       const float* __restrict__ a_param,
                                                       const float* __restrict__ nf,
                                                       const float* __restrict__ W1T,
                                                       const float* __restrict__ b1,
                                                       float* __restrict__ Bm) {
    int tid = threadIdx.x, bid = blockIdx.x;            // 512 blocks, 8 rows each
    int r0 = bid * 8;
    // pack: (col<<16) | f16(rsqrt(rowdeg[col])) ; slots >= dg stay zero (memset)
    for (int idx = tid; idx < 8 * BCAP; idx += 256) {
        int r = r0 + idx / BCAP, q = idx % BCAP;
        int dg = min(rowdeg[r], BCAP);
        if (q < dg) {
            unsigned col = bucket[r * BCAP + q];
            int rd = rowdeg[col];
            float rsj = (rd > 0) ? rsqrtf((float)rd) : 0.0f;
            union { _Float16 h; unsigned short u; } cv;
            cv.h = (_Float16)rsj;
            bucket[r * BCAP + q] = (col << 16) | (unsigned)cv.u;
        }
    }
    if (tid < 8) {
        int r = r0 + tid;
        float alpha = 0.5f + 0.5f * tanhf(2.0f * a_param[0]);
        int cd = coldeg[r];
        acoef[r] = (cd > 0) ? alpha * rsqrtf((float)cd) : 0.0f;
    }
    // linear1: 8 nodes, features staged in LDS, W1T coalesced
    __shared__ float sA[8 * 152];
    for (int idx = tid; idx < 8 * DIN; idx += 256) {
        int nd = idx / DIN, c = idx - nd * DIN;
        sA[nd * 152 + c] = nf[(r0 + nd) * DIN + c];
    }
    __syncthreads();
    int half = tid >> 7, d = tid & 127;
    float a0 = 0.f, a1 = 0.f, a2 = 0.f, a3 = 0.f;
    const float* sb8 = sA + half * 4 * 152;
    for (int kk = 0; kk < DIN; ++kk) {
        float wv = W1T[kk * DHID + d];
        a0 += sb8[0 * 152 + kk] * wv;
        a1 += sb8[1 * 152 + kk] * wv;
        a2 += sb8[2 * 152 + kk] * wv;
        a3 += sb8[3 * 152 + kk] * wv;
    }
    float bb = b1[d];
    int node0 = r0 + half * 4;
    Bm[(node0 + 0) * DHID + d] = a0 + bb;
    Bm[(node0 + 1) * DHID + d] = a1 + bb;
    Bm[(node0 + 2) * DHID + d] = a2 + bb;
    Bm[(node0 + 3) * DHID + d] = a3 + bb;
}

// ---- Richardson iteration: 2 waves/row split by COLUMNS (no sync), 1 float/lane,
// ---- 2-deep edge / 1-deep gather pipeline; 8192 waves = 8/SIMD occupancy ----
template<bool LAST>
__global__ __launch_bounds__(256) void spmv_kernel(const float* __restrict__ xin,
                                                   float* __restrict__ xout,
                                                   const float* __restrict__ Bm,
                                                   const float* __restrict__ prev2,
                                                   const unsigned* __restrict__ cc,
                                                   const int* __restrict__ rowdeg,
                                                   const float* __restrict__ acoef,
                                                   double* __restrict__ accd) {
    int tid = threadIdx.x;
    int wid = __builtin_amdgcn_readfirstlane(tid >> 6); // wave id 0..3 (SGPR)
    int lane = tid & 63;
    int r = blockIdx.x * 2 + (wid >> 1);                // two rows per block
    int co = ((wid & 1) << 6) + lane;                   // this wave's column 0..127
    int dg8 = (min(rowdeg[r], BCAP) + 7) & ~7;          // wave-uniform
    int nch = dg8 >> 3;                                 // 8-edge chunks
    const uint4* __restrict__ q = (const uint4*)(cc + r * BCAP);
    float ax = 0.f;
    // pipeline: edges 2 chunks ahead, gathers 1 chunk ahead (over-reads: zeroed slack)
    uint4 qa0 = q[0], qb0 = q[1];
    float v0 = xin[(qa0.x >> 16) * DHID + co];
    float v1 = xin[(qa0.y >> 16) * DHID + co];
    float v2 = xin[(qa0.z >> 16) * DHID + co];
    float v3 = xin[(qa0.w >> 16) * DHID + co];
    float v4 = xin[(qb0.x >> 16) * DHID + co];
    float v5 = xin[(qb0.y >> 16) * DHID + co];
    float v6 = xin[(qb0.z >> 16) * DHID + co];
    float v7 = xin[(qb0.w >> 16) * DHID + co];
    uint4 qa1 = q[2], qb1 = q[3];
    for (int c = 0; c < nch; ++c) {
        float w0 = xin[(qa1.x >> 16) * DHID + co];      // gathers for chunk c+1
        float w1 = xin[(qa1.y >> 16) * DHID + co];
        float w2 = xin[(qa1.z >> 16) * DHID + co];
        float w3 = xin[(qa1.w >> 16) * DHID + co];
        float w4 = xin[(qb1.x >> 16) * DHID + co];
        float w5 = xin[(qb1.y >> 16) * DHID + co];
        float w6 = xin[(qb1.z >> 16) * DHID + co];
        float w7 = xin[(qb1.w >> 16) * DHID + co];
        uint4 na = q[2 * c + 4], nb = q[2 * c + 5];     // edges for chunk c+2
        ax += h2f(qa0.x) * v0 + h2f(qa0.y) * v1 + h2f(qa0.z) * v2 + h2f(qa0.w) * v3
            + h2f(qb0.x) * v4 + h2f(qb0.y) * v5 + h2f(qb0.z) * v6 + h2f(qb0.w) * v7;
        qa0 = qa1; qb0 = qb1; qa1 = na; qb1 = nb;
        v0 = w0; v1 = w1; v2 = w2; v3 = w3;
        v4 = w4; v5 = w5; v6 = w6; v7 = w7;
    }
    int idx = r * DHID + co;
    float v = Bm[idx] + acoef[r] * ax;
    xout[idx] = v;
    if (LAST) {
        float xp = xin[idx];
        float p2 = prev2[idx];
        float dp = xp - p2;
        float dn = v - xp;
        double s0 = (double)dp * (double)dp;
        double s1 = (double)dn * (double)dp;
        __shared__ double sh0[256], sh1[256];
        sh0[tid] = s0; sh1[tid] = s1;
        __syncthreads();
        for (int off = 128; off > 0; off >>= 1) {
            if (tid < off) { sh0[tid] += sh0[tid + off]; sh1[tid] += sh1[tid + off]; }
            __syncthreads();
        }
        if (tid == 0) { atomicAdd(&accd[1], sh0[0]); atomicAdd(&accd[2], sh1[0]); }
    }
}

// ---------------- extrap + linear_d + f16 convert + pool (atomicMax) ----------------
__global__ __launch_bounds__(256) void post_kernel(const float* __restrict__ last,
                                                   const float* __restrict__ prev,
                                                   const double* __restrict__ accd,
                                                   const float* __restrict__ WdT,
                                                   const float* __restrict__ bd,
                                                   _Float16* __restrict__ yH,
                                                   unsigned* __restrict__ mcolu) {
    int tid = threadIdx.x, bid = blockIdx.x;
    double d0 = accd[1], d1 = accd[2];
    float lam = (d0 > 0.0) ? (float)(d1 / d0) : 0.0f;
    float den = 1.0f - lam;
    if (fabsf(den) < 1e-4f) den = (den < 0.0f) ? -1e-4f : 1e-4f;
    float sf = fminf(fmaxf(lam / den, -1e4f), 1e4f);
    __shared__ float sx[8 * DHID];
    for (int idx = tid; idx < 8 * DHID; idx += 256) {
        int node = bid * 8 + (idx >> 7), ccol = idx & 127;
        float l = last[node * DHID + ccol];
        sx[idx] = l + sf * (l - prev[node * DHID + ccol]);
    }
    __syncthreads();
    if (tid < DOUT) {
        float acc[8];
#pragma unroll
        for (int nd = 0; nd < 8; ++nd) acc[nd] = 0.f;
        for (int h = 0; h < DHID; ++h) {
            float wv = WdT[h * DOUT + tid];
#pragma unroll
            for (int nd = 0; nd < 8; ++nd) acc[nd] += sx[nd * DHID + h] * wv;
        }
        float bb = bd[tid];
        float lm = 0.0f;                                // relu floor
#pragma unroll
        for (int nd = 0; nd < 8; ++nd) {
            int node = bid * 8 + nd;
            float v = acc[nd] + bb;
            yH[node * KP + tid] = (_Float16)v;
            lm = fmaxf(lm, v);
        }
        atomicMax(&mcolu[tid], __float_as_uint(lm));    // nonneg float == uint order
    } else {
        int i2 = tid - DOUT;                            // zero pad cols 148..159
        if (i2 < 8 * (KP - DOUT)) {
            int node = bid * 8 + i2 / (KP - DOUT);
            int ccol = DOUT + i2 % (KP - DOUT);
            yH[node * KP + ccol] = (_Float16)0.0f;
        }
    }
}

// ---------------- simloss MFMA (528 tiles) + final outputs via last block ----------------
__global__ __launch_bounds__(256) void simloss_kernel(const _Float16* __restrict__ yH,
                                                      double* __restrict__ accd,
                                                      unsigned* __restrict__ cnt,
                                                      const unsigned* __restrict__ mcolu,
                                                      const float* __restrict__ W2,
                                                      const float* __restrict__ b2,
                                                      const float* __restrict__ a_param,
                                                      float* __restrict__ out) {
    int tid = threadIdx.x;
    int tb = blockIdx.x;
    int ti = 0, rem = tb;
    while (rem >= 32 - ti) { rem -= 32 - ti; ++ti; }
    int tj = ti + rem;
    int wid = tid >> 6, lane = tid & 63;
    int wr = wid >> 1, wc = wid & 1;
    int fr = lane & 15, kq = lane >> 4;
    const half8* __restrict__ ap =
        (const half8*)(yH + (size_t)(ti * 128 + wr * 64 + fr) * KP);
    const half8* __restrict__ bp =
        (const half8*)(yH + (size_t)(tj * 128 + wc * 64 + fr) * KP);
    f32x4 C[4][4];
#pragma unroll
    for (int m = 0; m < 4; ++m)
#pragma unroll
        for (int n = 0; n < 4; ++n) C[m][n] = (f32x4)0.0f;
#pragma unroll
    for (int kk = 0; kk < KP / 32; ++kk) {
        half8 a[4], bf[4];
#pragma unroll
        for (int m = 0; m < 4; ++m) a[m] = ap[m * 320 + kk * 4 + kq];
#pragma unroll
        for (int n = 0; n < 4; ++n) bf[n] = bp[n * 320 + kk * 4 + kq];
#pragma unroll
        for (int m = 0; m < 4; ++m)
#pragma unroll
            for (int n = 0; n < 4; ++n)
                C[m][n] = __builtin_amdgcn_mfma_f32_16x16x32_f16(a[m], bf[n], C[m][n], 0, 0, 0);
    }
    const float inv = 0.0883883476483184405f;           // 1/sqrt(128)
    float wgt = (ti == tj) ? 1.0f : 2.0f;
    float lsum = 0.0f;
    int rq = kq * 4;
#pragma unroll
    for (int m = 0; m < 4; ++m)
#pragma unroll
        for (int n = 0; n < 4; ++n)
#pragma unroll
            for (int reg = 0; reg < 4; ++reg) {
                int gi = ti * 128 + wr * 64 + m * 16 + rq + reg;
                int gj = tj * 128 + wc * 64 + n * 16 + fr;
                float v = C[m][n][reg] * inv;
                if (gi != gj && v > 0.0f) lsum += wgt * v;
            }
    for (int o2 = 32; o2 > 0; o2 >>= 1) lsum += __shfl_down(lsum, o2);
    __shared__ float ws[4];
    __shared__ bool lastblk;
    if ((tid & 63) == 0) ws[tid >> 6] = lsum;
    __syncthreads();
    if (tid == 0) {
        atomicAdd(&accd[0], (double)(ws[0] + ws[1] + ws[2] + ws[3]));
        __threadfence();
        unsigned r = __hip_atomic_fetch_add(&cnt[1], 1u, __ATOMIC_ACQ_REL,
                                            __HIP_MEMORY_SCOPE_AGENT);
        lastblk = (r == 527u);
    }
    __syncthreads();
    if (lastblk && tid < 64) {
        float alpha = 0.5f + 0.5f * tanhf(2.0f * a_param[0]);
        float oma = 1.0f - alpha;
        float s0 = 0.0f, s1 = 0.0f;
        for (int o = tid; o < DOUT; o += 64) {
            float p = __uint_as_float(mcolu[o]);        // already relu'd
            s0 += p * W2[o];
            s1 += p * W2[DOUT + o];
        }
        for (int off = 32; off > 0; off >>= 1) {
            s0 += __shfl_down(s0, off);
            s1 += __shfl_down(s1, off);
        }
        if (tid == 0) {
            double loss = __hip_atomic_load(&accd[0], __ATOMIC_RELAXED,
                                            __HIP_MEMORY_SCOPE_AGENT);
            out[0] = b2[0] + oma * s0;
            out[1] = b2[1] + oma * s1;
            out[2] = (float)(loss / (4096.0 * 4095.0));
        }
    }
}

extern "C" void kernel_launch(void* const* d_in, const int* in_sizes, int n_in,
                              void* d_out, int out_size, void* d_ws, size_t ws_size,
                              hipStream_t stream) {
    (void)in_sizes; (void)n_in; (void)out_size; (void)ws_size;
    const float* node_feat  = (const float*)d_in[0];
    const int*   edge_index = (const int*)d_in[1];   // harness converts int64 -> int32
    const float* W1         = (const float*)d_in[3];
    const float* b1         = (const float*)d_in[4];
    const float* a_param    = (const float*)d_in[5];
    const float* Wd         = (const float*)d_in[6];
    const float* bd         = (const float*)d_in[7];
    const float* W2         = (const float*)d_in[8];
    const float* b2         = (const float*)d_in[9];
    float*       out        = (float*)d_out;

    char* w = (char*)d_ws;
    size_t off = 0;
    auto alloc = [&](size_t bytes) -> char* {
        char* p = w + off;
        off = (off + bytes + 255) & ~(size_t)255;
        return p;
    };
    // zeroed region: accd, cnt, rowdeg, coldeg, mcolu, bitmap, bucket(+slack)
    double*   accd    = (double*)   alloc(8 * sizeof(double));   // [0]=loss,[1,2]=dots
    unsigned* cnt     = (unsigned*) alloc(16 * sizeof(unsigned));// [1]=simloss done ctr
    int*      rowdeg  = (int*)      alloc(N_NODES * 4);
    int*      coldeg  = (int*)      alloc(N_NODES * 4);
    unsigned* mcolu   = (unsigned*) alloc(256 * 4);
    unsigned* bitmap  = (unsigned*) alloc((size_t)N_NODES * N_NODES / 8);    // 2 MB
    unsigned* bucket  = (unsigned*) alloc((size_t)N_NODES * BCAP * 4 + 1024); // 1.25 MB + slack
    size_t zero_end = off;
    float*    acoef   = (float*)    alloc(N_NODES * 4);
    float*    W1T     = (float*)    alloc(DIN * DHID * 4);
    float*    WdT     = (float*)    alloc(DHID * DOUT * 4);
    float*    Bm      = (float*)    alloc(N_NODES * DHID * 4);
    float*    Y0      = (float*)    alloc(N_NODES * DHID * 4);
    float*    Y1      = (float*)    alloc(N_NODES * DHID * 4);
    float*    Y2      = (float*)    alloc(N_NODES * DHID * 4);
    _Float16* yH      = (_Float16*) alloc((size_t)N_NODES * KP * 2);

    hipMemsetAsync(w, 0, zero_end, stream);

    prep_kernel<<<N_EDGES / 256, 256, 0, stream>>>(edge_index, W1, Wd, W1T, WdT,
                                                   bitmap, bucket, rowdeg, coldeg);
    finalize_kernel<<<N_NODES / 8, 256, 0, stream>>>(bucket, rowdeg, coldeg, acoef,
                                                     a_param, node_feat, W1T, b1, Bm);

    float* rot[3] = {Y0, Y1, Y2};
    const float* cur = Bm;
    for (int it = 0; it < NITER - 1; ++it) {
        float* dst = rot[it % 3];
        spmv_kernel<false><<<N_NODES / 2, 256, 0, stream>>>(cur, dst, Bm, nullptr, bucket,
                                                            rowdeg, acoef, accd);
        cur = dst;
    }
    float* lastb = rot[(NITER - 1) % 3];
    float* prevb = rot[(NITER - 2) % 3];
    float* prev2 = rot[(NITER - 3) % 3];
    spmv_kernel<true><<<N_NODES / 2, 256, 0, stream>>>(cur, lastb, Bm, prev2, bucket,
                                                       rowdeg, acoef, accd);

    post_kernel<<<N_NODES / 8, 256, 0, stream>>>(lastb, prevb, accd, WdT, bd, yH, mcolu);
    simloss_kernel<<<528, 256, 0, stream>>>(yH, accd, cnt, mcolu, W2, b2, a_param, out);
}

// Round 14
// 157.328 us; speedup vs baseline: 1.1863x; 1.1863x over previous
//
#include <hip/hip_runtime.h>
#include <hip/hip_bf16.h>
#include <math.h>

#define N_NODES 4096
#define N_EDGES 131072
#define BCAP 80                        // bucket capacity per row (Poisson(32): P(>80)~1e-12)
#define DIN 148
#define DHID 128
#define DOUT 148
#define KP 160
#define NITER 6

typedef __attribute__((ext_vector_type(8))) _Float16 half8;
typedef __attribute__((ext_vector_type(4))) float f32x4;

__device__ inline float h2f(unsigned e) {
    union { unsigned short u; _Float16 h; } cv;
    cv.u = (unsigned short)(e & 0xffffu);
    return (float)cv.h;
}
__device__ inline float2 h2f2(unsigned p) {
    union { unsigned u; _Float16 h[2]; } cv; cv.u = p;
    return make_float2((float)cv.h[0], (float)cv.h[1]);
}
__device__ inline unsigned f2h2(float x, float y) {
    union { unsigned u; _Float16 h[2]; } cv;
    cv.h[0] = (_Float16)x; cv.h[1] = (_Float16)y;
    return cv.u;
}

// ---------------- prep: weight transposes + dedup into fixed-stride buckets ----------------
__global__ __launch_bounds__(256) void prep_kernel(const int* __restrict__ ei,
                                                   const float* __restrict__ W1,
                                                   const float* __restrict__ Wd,
                                                   float* __restrict__ W1T,
                                                   float* __restrict__ WdT,
                                                   unsigned* __restrict__ bitmap,
                                                   unsigned* __restrict__ bucket,
                                                   int* __restrict__ rowdeg,
                                                   int* __restrict__ coldeg) {
    int gtid = blockIdx.x * 256 + threadIdx.x;          // 0..131071
    if (gtid < DIN * DHID) {                            // W1T[k*128+d] = W1[d*148+k]
        int kk = gtid >> 7, d = gtid & 127;
        W1T[gtid] = W1[d * DIN + kk];
    } else if (gtid < DIN * DHID + DHID * DOUT) {       // WdT[h*148+o] = Wd[o*128+h]
        int i2 = gtid - DIN * DHID;
        int h = i2 / DOUT, o = i2 - h * DOUT;
        WdT[i2] = Wd[o * DHID + h];
    }
    int i = ei[gtid] & (N_NODES - 1);
    int j = ei[gtid + N_EDGES] & (N_NODES - 1);
    unsigned pos = (unsigned)i * (unsigned)N_NODES + (unsigned)j;
    unsigned w = pos >> 5, m = 1u << (pos & 31u);
    unsigned old = atomicOr(&bitmap[w], m);
    if (!(old & m)) {
        int p = atomicAdd(&rowdeg[i], 1);
        if (p < BCAP) bucket[i * BCAP + p] = (unsigned)j;
        atomicAdd(&coldeg[j], 1);
    }
}

// ------ finalize: pack coefs + acoef + linear1 (16 nodes/block; emits Bm f32 and Bh f16) ------
__global__ __launch_bounds__(256) void finalize_kernel(unsigned* __restrict__ bucket,
                                                       const int* __restrict__ rowdeg,
                                                       const int* __restrict__ coldeg,
                                                       float* __restrict__ acoef,
                                                       const float* __restrict__ a_param,
                                                       const float* __restrict__ nf,
                                                       const float* __restrict__ W1T,
                                                       const float* __restrict__ b1,
                                                       float* __restrict__ Bm,
                                                       unsigned* __restrict__ Bh) {
    int tid = threadIdx.x, bid = blockIdx.x;            // 256 blocks, 16 rows each
    int r0 = bid * 16;
    // pack: (col<<16) | f16(rsqrt(rowdeg[col])) ; slots >= dg stay zero (memset)
    for (int idx = tid; idx < 16 * BCAP; idx += 256) {
        int r = r0 + idx / BCAP, q = idx % BCAP;
        int dg = min(rowdeg[r], BCAP);
        if (q < dg) {
            unsigned col = bucket[r * BCAP + q];
            int rd = rowdeg[col];
            float rsj = (rd > 0) ? rsqrtf((float)rd) : 0.0f;
            union { _Float16 h; unsigned short u; } cv;
            cv.h = (_Float16)rsj;
            bucket[r * BCAP + q] = (col << 16) | (unsigned)cv.u;
        }
    }
    if (tid < 16) {
        int r = r0 + tid;
        float alpha = 0.5f + 0.5f * tanhf(2.0f * a_param[0]);
        int cd = coldeg[r];
        acoef[r] = (cd > 0) ? alpha * rsqrtf((float)cd) : 0.0f;
    }
    // linear1: 16 nodes, features staged in LDS, W1T coalesced
    __shared__ float sA[16 * 152];                      // 9.7 KB
    __shared__ float sB[16 * 128];                      // 8 KB
    for (int idx = tid; idx < 16 * DIN; idx += 256) {
        int nd = idx / DIN, c = idx - nd * DIN;
        sA[nd * 152 + c] = nf[(r0 + nd) * DIN + c];
    }
    __syncthreads();
    int half = tid >> 7, d = tid & 127;
    float a[8];
#pragma unroll
    for (int n = 0; n < 8; ++n) a[n] = 0.f;
    const float* sb8 = sA + half * 8 * 152;
    for (int kk = 0; kk < DIN; ++kk) {
        float wv = W1T[kk * DHID + d];
#pragma unroll
        for (int n = 0; n < 8; ++n) a[n] += sb8[n * 152 + kk] * wv;
    }
    float bb = b1[d];
#pragma unroll
    for (int n = 0; n < 8; ++n) {
        int nd = half * 8 + n;
        float v = a[n] + bb;
        Bm[(r0 + nd) * DHID + d] = v;
        sB[nd * 128 + d] = v;
    }
    __syncthreads();
    for (int idx = tid; idx < 16 * 64; idx += 256) {
        int nd = idx >> 6, dp = idx & 63;
        Bh[(r0 + nd) * 64 + dp] = f2h2(sB[nd * 128 + 2 * dp], sB[nd * 128 + 2 * dp + 1]);
    }
}

// ---- Richardson iteration: 1 row/wave, 2-col lanes, 2-deep edge / 1-deep gather pipeline.
// ---- INH: gather from f16-packed x (256B/row); OUTH: store f16-packed. LAST: + dots (f32 only).
template<bool INH, bool OUTH, bool LAST>
__global__ __launch_bounds__(256) void spmv_kernel(const void* __restrict__ xin_,
                                                   void* __restrict__ xout_,
                                                   const float* __restrict__ Bm,
                                                   const float* __restrict__ prev2,
                                                   const unsigned* __restrict__ cc,
                                                   const int* __restrict__ rowdeg,
                                                   const float* __restrict__ acoef,
                                                   double* __restrict__ accd) {
    int tid = threadIdx.x;
    int wid = __builtin_amdgcn_readfirstlane(tid >> 6); // wave id 0..3 (SGPR)
    int lane = tid & 63;
    int r = blockIdx.x * 4 + wid;                       // one row per wave
    int dg8 = (min(rowdeg[r], BCAP) + 7) & ~7;          // wave-uniform
    int nch = dg8 >> 3;                                 // 8-edge chunks
    const uint4* __restrict__ q = (const uint4*)(cc + r * BCAP);
    const unsigned* __restrict__ xh = (const unsigned*)xin_;
    const float2* __restrict__ x2 = (const float2*)xin_;
    auto ldx = [&](unsigned e) -> float2 {
        int col = (int)(e >> 16);
        if constexpr (INH) return h2f2(xh[col * 64 + lane]);
        else return x2[col * 64 + lane];
    };
    float ax = 0.f, ay = 0.f;
    // pipeline: edges 2 chunks ahead, gathers 1 chunk ahead (over-reads land in zeroed slack)
    uint4 qa0 = q[0], qb0 = q[1];
    float2 v0 = ldx(qa0.x), v1 = ldx(qa0.y), v2 = ldx(qa0.z), v3 = ldx(qa0.w);
    float2 v4 = ldx(qb0.x), v5 = ldx(qb0.y), v6 = ldx(qb0.z), v7 = ldx(qb0.w);
    uint4 qa1 = q[2], qb1 = q[3];
    for (int c = 0; c < nch; ++c) {
        float2 w0 = ldx(qa1.x), w1 = ldx(qa1.y), w2 = ldx(qa1.z), w3 = ldx(qa1.w);
        float2 w4 = ldx(qb1.x), w5 = ldx(qb1.y), w6 = ldx(qb1.z), w7 = ldx(qb1.w);
        uint4 na = q[2 * c + 4], nb = q[2 * c + 5];     // edges for chunk c+2
        float c0 = h2f(qa0.x), c1 = h2f(qa0.y), c2f = h2f(qa0.z), c3 = h2f(qa0.w);
        float c4 = h2f(qb0.x), c5 = h2f(qb0.y), c6 = h2f(qb0.z), c7 = h2f(qb0.w);
        ax += c0 * v0.x + c1 * v1.x + c2f * v2.x + c3 * v3.x
            + c4 * v4.x + c5 * v5.x + c6 * v6.x + c7 * v7.x;
        ay += c0 * v0.y + c1 * v1.y + c2f * v2.y + c3 * v3.y
            + c4 * v4.y + c5 * v5.y + c6 * v6.y + c7 * v7.y;
        qa0 = qa1; qb0 = qb1; qa1 = na; qb1 = nb;
        v0 = w0; v1 = w1; v2 = w2; v3 = w3;
        v4 = w4; v5 = w5; v6 = w6; v7 = w7;
    }
    float ac = acoef[r];
    int idx = r * 64 + lane;
    float2 b = ((const float2*)Bm)[idx];
    float vx = b.x + ac * ax, vy = b.y + ac * ay;
    if constexpr (OUTH) {
        ((unsigned*)xout_)[idx] = f2h2(vx, vy);
    } else {
        ((float2*)xout_)[idx] = make_float2(vx, vy);
    }
    if constexpr (LAST) {                               // f32-in only
        float2 xp = ((const float2*)xin_)[idx];
        float2 p2 = ((const float2*)prev2)[idx];
        float dpx = xp.x - p2.x, dpy = xp.y - p2.y;
        float dnx = vx - xp.x, dny = vy - xp.y;
        double s0 = (double)dpx * dpx + (double)dpy * dpy;
        double s1 = (double)dnx * dpx + (double)dny * dpy;
        __shared__ double sh0[256], sh1[256];
        sh0[tid] = s0; sh1[tid] = s1;
        __syncthreads();
        for (int off = 128; off > 0; off >>= 1) {
            if (tid < off) { sh0[tid] += sh0[tid + off]; sh1[tid] += sh1[tid + off]; }
            __syncthreads();
        }
        if (tid == 0) { atomicAdd(&accd[1], sh0[0]); atomicAdd(&accd[2], sh1[0]); }
    }
}

// ---------------- post: extrap + linear_d + f16 convert + pool (16 nodes/block) ----------------
__global__ __launch_bounds__(256) void post_kernel(const float* __restrict__ last,
                                                   const float* __restrict__ prev,
                                                   const double* __restrict__ accd,
                                                   const float* __restrict__ WdT,
                                                   const float* __restrict__ bd,
                                                   _Float16* __restrict__ yH,
                                                   unsigned* __restrict__ mcolu) {
    int tid = threadIdx.x, bid = blockIdx.x;            // 256 blocks, 16 nodes each
    int r0 = bid * 16;
    double d0 = accd[1], d1 = accd[2];
    float lam = (d0 > 0.0) ? (float)(d1 / d0) : 0.0f;
    float den = 1.0f - lam;
    if (fabsf(den) < 1e-4f) den = (den < 0.0f) ? -1e-4f : 1e-4f;
    float sf = fminf(fmaxf(lam / den, -1e4f), 1e4f);
    __shared__ float sx[16 * DHID];                     // 8 KB
    for (int idx = tid; idx < 16 * DHID; idx += 256) {
        int node = r0 + (idx >> 7), ccol = idx & 127;
        float l = last[node * DHID + ccol];
        sx[idx] = l + sf * (l - prev[node * DHID + ccol]);
    }
    __syncthreads();
    for (int idx = tid; idx < 16 * (KP - DOUT); idx += 256) {   // zero pad cols 148..159
        int node = r0 + idx / (KP - DOUT);
        int ccol = DOUT + idx % (KP - DOUT);
        yH[node * KP + ccol] = (_Float16)0.0f;
    }
    if (tid < DOUT) {
        float acc[16];
#pragma unroll
        for (int nd = 0; nd < 16; ++nd) acc[nd] = 0.f;
        for (int h = 0; h < DHID; ++h) {
            float wv = WdT[h * DOUT + tid];
#pragma unroll
            for (int nd = 0; nd < 16; ++nd) acc[nd] += sx[nd * DHID + h] * wv;
        }
        float bb = bd[tid];
        float lm = 0.0f;                                // relu floor
#pragma unroll
        for (int nd = 0; nd < 16; ++nd) {
            float v = acc[nd] + bb;
            yH[(r0 + nd) * KP + tid] = (_Float16)v;
            lm = fmaxf(lm, v);
        }
        atomicMax(&mcolu[tid], __float_as_uint(lm));    // nonneg float == uint order
    }
}

// ---------------- simloss MFMA (528 tiles) + final outputs via last block ----------------
__global__ __launch_bounds__(256) void simloss_kernel(const _Float16* __restrict__ yH,
                                                      double* __restrict__ accd,
                                                      unsigned* __restrict__ cnt,
                                                      const unsigned* __restrict__ mcolu,
                                                      const float* __restrict__ W2,
                                                      const float* __restrict__ b2,
                                                      const float* __restrict__ a_param,
                                                      float* __restrict__ out) {
    int tid = threadIdx.x;
    int tb = blockIdx.x;
    int ti = 0, rem = tb;
    while (rem >= 32 - ti) { rem -= 32 - ti; ++ti; }
    int tj = ti + rem;
    int wid = tid >> 6, lane = tid & 63;
    int wr = wid >> 1, wc = wid & 1;
    int fr = lane & 15, kq = lane >> 4;
    const half8* __restrict__ ap =
        (const half8*)(yH + (size_t)(ti * 128 + wr * 64 + fr) * KP);
    const half8* __restrict__ bp =
        (const half8*)(yH + (size_t)(tj * 128 + wc * 64 + fr) * KP);
    f32x4 C[4][4];
#pragma unroll
    for (int m = 0; m < 4; ++m)
#pragma unroll
        for (int n = 0; n < 4; ++n) C[m][n] = (f32x4)0.0f;
#pragma unroll
    for (int kk = 0; kk < KP / 32; ++kk) {
        half8 a[4], bf[4];
#pragma unroll
        for (int m = 0; m < 4; ++m) a[m] = ap[m * 320 + kk * 4 + kq];
#pragma unroll
        for (int n = 0; n < 4; ++n) bf[n] = bp[n * 320 + kk * 4 + kq];
#pragma unroll
        for (int m = 0; m < 4; ++m)
#pragma unroll
            for (int n = 0; n < 4; ++n)
                C[m][n] = __builtin_amdgcn_mfma_f32_16x16x32_f16(a[m], bf[n], C[m][n], 0, 0, 0);
    }
    const float inv = 0.0883883476483184405f;           // 1/sqrt(128)
    float wgt = (ti == tj) ? 1.0f : 2.0f;
    float lsum = 0.0f;
    int rq = kq * 4;
#pragma unroll
    for (int m = 0; m < 4; ++m)
#pragma unroll
        for (int n = 0; n < 4; ++n)
#pragma unroll
            for (int reg = 0; reg < 4; ++reg) {
                int gi = ti * 128 + wr * 64 + m * 16 + rq + reg;
                int gj = tj * 128 + wc * 64 + n * 16 + fr;
                float v = C[m][n][reg] * inv;
                if (gi != gj && v > 0.0f) lsum += wgt * v;
            }
    for (int o2 = 32; o2 > 0; o2 >>= 1) lsum += __shfl_down(lsum, o2);
    __shared__ float ws[4];
    __shared__ bool lastblk;
    if ((tid & 63) == 0) ws[tid >> 6] = lsum;
    __syncthreads();
    if (tid == 0) {
        atomicAdd(&accd[0], (double)(ws[0] + ws[1] + ws[2] + ws[3]));
        __threadfence();
        unsigned r = __hip_atomic_fetch_add(&cnt[1], 1u, __ATOMIC_ACQ_REL,
                                            __HIP_MEMORY_SCOPE_AGENT);
        lastblk = (r == 527u);
    }
    __syncthreads();
    if (lastblk && tid < 64) {
        float alpha = 0.5f + 0.5f * tanhf(2.0f * a_param[0]);
        float oma = 1.0f - alpha;
        float s0 = 0.0f, s1 = 0.0f;
        for (int o = tid; o < DOUT; o += 64) {
            float p = __uint_as_float(mcolu[o]);        // already relu'd
            s0 += p * W2[o];
            s1 += p * W2[DOUT + o];
        }
        for (int off = 32; off > 0; off >>= 1) {
            s0 += __shfl_down(s0, off);
            s1 += __shfl_down(s1, off);
        }
        if (tid == 0) {
            double loss = __hip_atomic_load(&accd[0], __ATOMIC_RELAXED,
                                            __HIP_MEMORY_SCOPE_AGENT);
            out[0] = b2[0] + oma * s0;
            out[1] = b2[1] + oma * s1;
            out[2] = (float)(loss / (4096.0 * 4095.0));
        }
    }
}

extern "C" void kernel_launch(void* const* d_in, const int* in_sizes, int n_in,
                              void* d_out, int out_size, void* d_ws, size_t ws_size,
                              hipStream_t stream) {
    (void)in_sizes; (void)n_in; (void)out_size; (void)ws_size;
    const float* node_feat  = (const float*)d_in[0];
    const int*   edge_index = (const int*)d_in[1];   // harness converts int64 -> int32
    const float* W1         = (const float*)d_in[3];
    const float* b1         = (const float*)d_in[4];
    const float* a_param    = (const float*)d_in[5];
    const float* Wd         = (const float*)d_in[6];
    const float* bd         = (const float*)d_in[7];
    const float* W2         = (const float*)d_in[8];
    const float* b2         = (const float*)d_in[9];
    float*       out        = (float*)d_out;

    char* w = (char*)d_ws;
    size_t off = 0;
    auto alloc = [&](size_t bytes) -> char* {
        char* p = w + off;
        off = (off + bytes + 255) & ~(size_t)255;
        return p;
    };
    // zeroed region: accd, cnt, rowdeg, coldeg, mcolu, bitmap, bucket(+slack)
    double*   accd    = (double*)   alloc(8 * sizeof(double));   // [0]=loss,[1,2]=dots
    unsigned* cnt     = (unsigned*) alloc(16 * sizeof(unsigned));// [1]=simloss done ctr
    int*      rowdeg  = (int*)      alloc(N_NODES * 4);
    int*      coldeg  = (int*)      alloc(N_NODES * 4);
    unsigned* mcolu   = (unsigned*) alloc(256 * 4);
    unsigned* bitmap  = (unsigned*) alloc((size_t)N_NODES * N_NODES / 8);    // 2 MB
    unsigned* bucket  = (unsigned*) alloc((size_t)N_NODES * BCAP * 4 + 1024); // 1.25 MB + slack
    size_t zero_end = off;
    float*    acoef   = (float*)    alloc(N_NODES * 4);
    float*    W1T     = (float*)    alloc(DIN * DHID * 4);
    float*    WdT     = (float*)    alloc(DHID * DOUT * 4);
    float*    Bm      = (float*)    alloc(N_NODES * DHID * 4);
    unsigned* Bh      = (unsigned*) alloc((size_t)N_NODES * 64 * 4);  // f16-packed B
    unsigned* H0      = (unsigned*) alloc((size_t)N_NODES * 64 * 4);  // f16-packed x
    unsigned* H1      = (unsigned*) alloc((size_t)N_NODES * 64 * 4);
    float*    Y0      = (float*)    alloc(N_NODES * DHID * 4);
    float*    Y1      = (float*)    alloc(N_NODES * DHID * 4);
    float*    Y2      = (float*)    alloc(N_NODES * DHID * 4);
    _Float16* yH      = (_Float16*) alloc((size_t)N_NODES * KP * 2);

    hipMemsetAsync(w, 0, zero_end, stream);

    prep_kernel<<<N_EDGES / 256, 256, 0, stream>>>(edge_index, W1, Wd, W1T, WdT,
                                                   bitmap, bucket, rowdeg, coldeg);
    finalize_kernel<<<N_NODES / 16, 256, 0, stream>>>(bucket, rowdeg, coldeg, acoef,
                                                      a_param, node_feat, W1T, b1, Bm, Bh);

    const int GB = N_NODES / 4;
    // x1..x3 in f16 (halved gather traffic); x4..x6 in f32 (clean extrapolation)
    spmv_kernel<true,  true,  false><<<GB, 256, 0, stream>>>(Bh, H0, Bm, nullptr, bucket, rowdeg, acoef, accd);
    spmv_kernel<true,  true,  false><<<GB, 256, 0, stream>>>(H0, H1, Bm, nullptr, bucket, rowdeg, acoef, accd);
    spmv_kernel<true,  true,  false><<<GB, 256, 0, stream>>>(H1, H0, Bm, nullptr, bucket, rowdeg, acoef, accd);
    spmv_kernel<true,  false, false><<<GB, 256, 0, stream>>>(H0, Y0, Bm, nullptr, bucket, rowdeg, acoef, accd);
    spmv_kernel<false, false, false><<<GB, 256, 0, stream>>>(Y0, Y1, Bm, nullptr, bucket, rowdeg, acoef, accd);
    spmv_kernel<false, false, true ><<<GB, 256, 0, stream>>>(Y1, Y2, Bm, Y0, bucket, rowdeg, acoef, accd);

    post_kernel<<<N_NODES / 16, 256, 0, stream>>>(Y2, Y1, accd, WdT, bd, yH, mcolu);
    simloss_kernel<<<528, 256, 0, stream>>>(yH, accd, cnt, mcolu, W2, b2, a_param, out);
}